// Round 9
// baseline (8215.910 us; speedup 1.0000x reference)
//
#include <hip/hip_runtime.h>
#include <hip/hip_bf16.h>

typedef __attribute__((ext_vector_type(8))) short   short8;
typedef __attribute__((ext_vector_type(4))) float   float4_;
typedef __attribute__((ext_vector_type(2))) float   float2_;

// ---------------- workspace layout (bytes) ----------------
#define WPACK_OFF   0
#define WPACK_BYTES 786432                    // 1024 rows x 384 k x 2B, A-frag packed
#define HBUF_OFF    786432
#define HBUF_BYTES  1048576                   // 4 slots x 32768 chunks x 8B
#define BIAS_OFF    (HBUF_OFF + HBUF_BYTES)
#define BIAS_BYTES  4096

#define SLOT_CH 32768                         // chunks per step-slot (16grp*16b*128np)
// chunk = { low dword: 2 x bf16 h ; high dword: u32 step tag } — ONE 8B atomic.
// Skew proof: every block consumes ALL group peers' slices each step -> no block
// can be >1 step ahead of any peer -> 4 slots can never alias; tags are exact.

__device__ __forceinline__ unsigned short f2bf(float f) {
  unsigned int u = __float_as_uint(f);
  u += 0x7fffu + ((u >> 16) & 1u);            // round-to-nearest-even
  return (unsigned short)(u >> 16);
}

// Pack W = [W_hh | W_ih] into MFMA A-fragment order, bf16.
// idx = ((((s*4+w)*2+m)*12)+kt)*64+lane ; block s owns rows gate*256 + [s*32,s*32+32).
__global__ void pack_w(const float* __restrict__ w_ih,
                       const float* __restrict__ w_hh,
                       unsigned short* __restrict__ wpack) {
  int idx = blockIdx.x * blockDim.x + threadIdx.x;
  if (idx >= 49152) return;
  int lane = idx & 63;
  int r1 = idx >> 6;
  int kt = r1 % 12;
  int r2 = r1 / 12;
  int m  = r2 & 1;          // mtile within slice (16 rows)
  int r3 = r2 >> 1;
  int w  = r3 & 3;          // gate (i,f,g,o) == wave
  int s  = r3 >> 2;         // slice 0..7
  int row = w * 256 + s * 32 + m * 16 + (lane & 15);
  int q = lane >> 4;
  short8 o;
#pragma unroll
  for (int j = 0; j < 8; ++j) {
    int kk = kt * 32 + q * 8 + j;             // 0..383
    float v = (kt < 8) ? w_hh[row * 256 + kk]
                       : w_ih[row * 128 + (kk - 256)];
    o[j] = (short)f2bf(v);
  }
  *(short8*)(wpack + (size_t)idx * 8) = o;
}

// Seed slot 0 with {h0 pair, tag=0}; bias = b_ih+b_hh. Slots 1..3 need no init:
// their poisoned tags (0xAAAAAAAA) never match any expected t < 1024.
__global__ void init_hb(const float* __restrict__ h0,
                        const float* __restrict__ b_ih,
                        const float* __restrict__ b_hh,
                        unsigned long long* __restrict__ hbuf,
                        float* __restrict__ bias) {
  int idx = blockIdx.x * blockDim.x + threadIdx.x;
  if (idx < 32768) {                           // chunk idx = b_glob*128 + npair
    int b_glob = idx >> 7;
    int np     = idx & 127;
    unsigned int d = (unsigned int)f2bf(h0[b_glob * 256 + 2 * np])
                   | ((unsigned int)f2bf(h0[b_glob * 256 + 2 * np + 1]) << 16);
    hbuf[idx] = (unsigned long long)d;         // tag = 0 in high dword
  } else if (idx < 33792) {
    int j = idx - 32768;
    bias[j] = b_ih[j] + b_hh[j];
  }
}

__device__ __forceinline__ float sigm_(float v) {
  return 1.f / (1.f + __expf(-v));
}
__device__ __forceinline__ float tanh_(float v) {
  return 1.f - 2.f / (__expf(2.f * v) + 1.f);  // robust at +-inf
}

__global__ __launch_bounds__(256, 1) void lstm_main(
    const float* __restrict__ x, const float* __restrict__ c0,
    const unsigned short* __restrict__ wpack, const float* __restrict__ bias,
    unsigned long long* hbuf, float* __restrict__ out) {

  const int tid  = threadIdx.x;
  const int w    = tid >> 6;       // wave == gate 0..3
  const int lane = tid & 63;
  const int q    = lane >> 4;
  const int bl   = lane & 15;

  const int id  = blockIdx.x;
  const int grp = id >> 3;                  // batch group 0..15
  const int s   = id & 7;                   // n-slice 0..7 (32 elems)

  // combiner-role constants: thread (np,b) owns h/c for n = s*32+2np+{0,1}, batch b
  const int np = tid >> 4;                  // 0..15
  const int b  = tid & 15;
  const int nglob   = s * 32 + 2 * np;
  const int bglob_c = grp * 16 + b;

  // ---- W fragments in VGPRs: 2 mtiles x 12 ktiles = 24 frags (96 regs) ----
  short8 wf[24];
  {
    const unsigned short* base =
        wpack + ((size_t)((s * 4 + w) * 24) * 64 + lane) * 8;
#pragma unroll
    for (int f = 0; f < 24; ++f)
      wf[f] = *(const short8*)(base + (size_t)f * 64 * 8);
  }
#pragma unroll
  for (int f = 0; f < 24; ++f)
    asm volatile("" : "+v"(wf[f]));          // pinned; 96 + ~120 live < 256

  // bias for gate w (acc init)
  float4_ bia[2];
#pragma unroll
  for (int m = 0; m < 2; ++m)
    bia[m] = *(const float4_*)(bias + w * 256 + s * 32 + m * 16 + q * 4);

  // c state (combiner role)
  float cst[2];
  cst[0] = c0[(size_t)bglob_c * 256 + nglob];
  cst[1] = c0[(size_t)bglob_c * 256 + nglob + 1];

  // x prefetch for t=0 (ktiles 8..11); B-frag batch = grp*16+bl (normal cached
  // loads — L2 absorbs the 8-blocks-per-group redundancy; nt made it HBM traffic)
  float4_ xr[8];
  {
    const float* xb = x + (size_t)(grp * 16 + bl) * 131072 + q * 8;
#pragma unroll
    for (int kx = 0; kx < 4; ++kx) {
      xr[kx * 2]     = *(const float4_*)(xb + kx * 32);
      xr[kx * 2 + 1] = *(const float4_*)(xb + kx * 32 + 4);
    }
  }

  // hbuf addressing (chunk = ull)
  const size_t hb_base = ((size_t)grp * 16 + bl) * 128;               // consumer
  const size_t my_ch   = ((size_t)grp * 16 + b) * 128 + s * 16 + np;  // producer

  // gate-exchange LDS: [gate][n_local 32][b 16+pad]
  __shared__ float glds[4][32][17];

  float hout[2];

#pragma unroll 1
  for (int t = 0; t < 1024; ++t) {
    // convert prefetched x -> bf16 frags (xr issued ~a full step ago)
    short8 xf[4];
#pragma unroll
    for (int kx = 0; kx < 4; ++kx) {
      short8 v;
#pragma unroll
      for (int e = 0; e < 4; ++e) {
        v[e]     = (short)f2bf(xr[kx * 2][e]);
        v[e + 4] = (short)f2bf(xr[kx * 2 + 1][e]);
      }
      xf[kx] = v;
    }

    // ---- poll h_t: tag==t means payload present (tag+data are one atomic) ----
    unsigned long long pl[32];
    {
      const unsigned long long* hb = hbuf + (size_t)(t & 3) * SLOT_CH + hb_base;
      const unsigned int tag = (unsigned int)t;
      for (;;) {
#pragma unroll
        for (int kt = 0; kt < 8; ++kt)
#pragma unroll
          for (int j = 0; j < 4; ++j)
            pl[kt * 4 + j] = __hip_atomic_load(hb + kt * 16 + q * 4 + j,
                                               __ATOMIC_RELAXED,
                                               __HIP_MEMORY_SCOPE_AGENT);
        bool ok = true;
#pragma unroll
        for (int i = 0; i < 32; ++i)
          ok &= ((unsigned int)(pl[i] >> 32) == tag);
        if (__all(ok)) break;
        __builtin_amdgcn_s_sleep(1);
      }
    }
    asm volatile("" ::: "memory");

    float4_ acc[2];
#pragma unroll
    for (int m = 0; m < 2; ++m) acc[m] = bia[m];

    // x contribution: ktiles 8..11
#pragma unroll
    for (int kx = 0; kx < 4; ++kx)
#pragma unroll
      for (int m = 0; m < 2; ++m)
        acc[m] = __builtin_amdgcn_mfma_f32_16x16x32_bf16(wf[m * 12 + 8 + kx], xf[kx], acc[m], 0, 0, 0);

    // h contribution: ktiles 0..7 (B-frag = 4 low dwords of the tagged chunks)
#pragma unroll
    for (int kt = 0; kt < 8; ++kt) {
      union { unsigned int u[4]; short8 v; } uu;
#pragma unroll
      for (int j = 0; j < 4; ++j)
        uu.u[j] = (unsigned int)pl[kt * 4 + j];
#pragma unroll
      for (int m = 0; m < 2; ++m)
        acc[m] = __builtin_amdgcn_mfma_f32_16x16x32_bf16(wf[m * 12 + kt], uu.v, acc[m], 0, 0, 0);
    }

    // publish gate-w pre-activations to LDS (C-layout: col=bl, row=q*4+r)
#pragma unroll
    for (int m = 0; m < 2; ++m)
#pragma unroll
      for (int r = 0; r < 4; ++r)
        glds[w][m * 16 + q * 4 + r][bl] = acc[m][r];

    __syncthreads();

    // x prefetch for NEXT step — after the barrier so no waitcnt drains it early
    {
      int tn = (t < 1023) ? (t + 1) : 1023;
      const float* xb = x + (size_t)(grp * 16 + bl) * 131072 + (size_t)tn * 128 + q * 8;
#pragma unroll
      for (int kx = 0; kx < 4; ++kx) {
        xr[kx * 2]     = *(const float4_*)(xb + kx * 32);
        xr[kx * 2 + 1] = *(const float4_*)(xb + kx * 32 + 4);
      }
    }

    // ---- combine all 4 gates for this thread's 2 (n,b) elements ----
    unsigned short hp[2];
#pragma unroll
    for (int dn = 0; dn < 2; ++dn) {
      int nl = 2 * np + dn;
      float iv = sigm_(glds[0][nl][b]);
      float fv = sigm_(glds[1][nl][b]);
      float gv = tanh_(glds[2][nl][b]);
      float ov = sigm_(glds[3][nl][b]);
      float cv = fv * cst[dn] + iv * gv;
      cst[dn] = cv;
      float hv = ov * tanh_(cv);
      hout[dn] = hv;
      hp[dn] = f2bf(hv);
    }

    // write h_{t+1}: ONE tagged 8B atomic store per thread, slot (t+1)&3
    {
      unsigned int d = (unsigned int)hp[0] | ((unsigned int)hp[1] << 16);
      unsigned long long hu = (unsigned long long)d
                            | ((unsigned long long)(unsigned int)(t + 1) << 32);
      unsigned long long* dst = hbuf + (size_t)((t + 1) & 3) * SLOT_CH + my_ch;
      __hip_atomic_store(dst, hu, __ATOMIC_RELAXED, __HIP_MEMORY_SCOPE_AGENT);
    }
  }

  // final h (fp32) -> d_out [1,B,H]
  {
    float2_ o2; o2[0] = hout[0]; o2[1] = hout[1];
    *(float2_*)(out + (size_t)bglob_c * 256 + nglob) = o2;
  }
}

extern "C" void kernel_launch(void* const* d_in, const int* in_sizes, int n_in,
                              void* d_out, int out_size, void* d_ws, size_t ws_size,
                              hipStream_t stream) {
  (void)in_sizes; (void)n_in; (void)out_size; (void)ws_size;
  const float* x    = (const float*)d_in[0];
  const float* h0   = (const float*)d_in[1];
  const float* c0   = (const float*)d_in[2];
  const float* w_ih = (const float*)d_in[3];
  const float* w_hh = (const float*)d_in[4];
  const float* b_ih = (const float*)d_in[5];
  const float* b_hh = (const float*)d_in[6];

  char* ws = (char*)d_ws;
  unsigned short*     wpack = (unsigned short*)(ws + WPACK_OFF);
  unsigned long long* hbuf  = (unsigned long long*)(ws + HBUF_OFF);
  float*              bias  = (float*)(ws + BIAS_OFF);

  pack_w<<<192, 256, 0, stream>>>(w_ih, w_hh, wpack);
  init_hb<<<132, 256, 0, stream>>>(h0, b_ih, b_hh, hbuf, bias);
  lstm_main<<<128, 256, 0, stream>>>(x, c0, wpack, bias, hbuf, (float*)d_out);
}

// Round 10
// 8169.599 us; speedup vs baseline: 1.0057x; 1.0057x over previous
//
#include <hip/hip_runtime.h>
#include <hip/hip_bf16.h>

typedef __attribute__((ext_vector_type(8))) short   short8;
typedef __attribute__((ext_vector_type(4))) float   float4_;
typedef __attribute__((ext_vector_type(2))) float   float2_;

// ---------------- workspace layout (bytes) ----------------
#define WPACK_OFF   0
#define WPACK_BYTES 786432                    // 1024 rows x 384 k x 2B, A-frag packed
#define HBUF_OFF    786432
#define HBUF_BYTES  1048576                   // 4 slots x 32768 chunks x 8B
#define BIAS_OFF    (HBUF_OFF + HBUF_BYTES)
#define BIAS_BYTES  4096

#define SLOT_CH 32768                         // chunks per step-slot (16grp*16b*128np)
// chunk = { low dword: 2 x bf16 h ; high dword: u32 step tag } — ONE 8B atomic.
// Skew proof: every block consumes ALL group peers' slices each step -> no block
// can be >1 step ahead of any peer -> 4 slots can never alias; tags are exact.

__device__ __forceinline__ unsigned short f2bf(float f) {
  unsigned int u = __float_as_uint(f);
  u += 0x7fffu + ((u >> 16) & 1u);            // round-to-nearest-even
  return (unsigned short)(u >> 16);
}

// Pack W = [W_hh | W_ih] into MFMA A-fragment order, bf16.
// idx = ((((s*4+w)*2+m)*12)+kt)*64+lane ; slice s owns rows gate*256 + [s*32,s*32+32).
__global__ void pack_w(const float* __restrict__ w_ih,
                       const float* __restrict__ w_hh,
                       unsigned short* __restrict__ wpack) {
  int idx = blockIdx.x * blockDim.x + threadIdx.x;
  if (idx >= 49152) return;
  int lane = idx & 63;
  int r1 = idx >> 6;
  int kt = r1 % 12;
  int r2 = r1 / 12;
  int m  = r2 & 1;          // mtile within slice (16 rows)
  int r3 = r2 >> 1;
  int w  = r3 & 3;          // gate (i,f,g,o) == wave
  int s  = r3 >> 2;         // slice 0..7
  int row = w * 256 + s * 32 + m * 16 + (lane & 15);
  int q = lane >> 4;
  short8 o;
#pragma unroll
  for (int j = 0; j < 8; ++j) {
    int kk = kt * 32 + q * 8 + j;             // 0..383
    float v = (kt < 8) ? w_hh[row * 256 + kk]
                       : w_ih[row * 128 + (kk - 256)];
    o[j] = (short)f2bf(v);
  }
  *(short8*)(wpack + (size_t)idx * 8) = o;
}

// Seed slot 0 with {h0 pair, tag=0}; bias = b_ih+b_hh. Slots 1..3 need no init:
// their poisoned tags (0xAAAAAAAA) never match any expected t < 1024.
__global__ void init_hb(const float* __restrict__ h0,
                        const float* __restrict__ b_ih,
                        const float* __restrict__ b_hh,
                        unsigned long long* __restrict__ hbuf,
                        float* __restrict__ bias) {
  int idx = blockIdx.x * blockDim.x + threadIdx.x;
  if (idx < 32768) {                           // chunk idx = b_glob*128 + npair
    int b_glob = idx >> 7;
    int np     = idx & 127;
    unsigned int d = (unsigned int)f2bf(h0[b_glob * 256 + 2 * np])
                   | ((unsigned int)f2bf(h0[b_glob * 256 + 2 * np + 1]) << 16);
    hbuf[idx] = (unsigned long long)d;         // tag = 0 in high dword
  } else if (idx < 33792) {
    int j = idx - 32768;
    bias[j] = b_ih[j] + b_hh[j];
  }
}

__device__ __forceinline__ float sigm_(float v) {
  return 1.f / (1.f + __expf(-v));
}
__device__ __forceinline__ float tanh_(float v) {
  return 1.f - 2.f / (__expf(2.f * v) + 1.f);  // robust at +-inf
}

__global__ __launch_bounds__(256, 1) void lstm_main(
    const float* __restrict__ x, const float* __restrict__ c0,
    const unsigned short* __restrict__ wpack, const float* __restrict__ bias,
    unsigned long long* hbuf, float* __restrict__ out) {

  const int tid  = threadIdx.x;
  const int w    = tid >> 6;       // wave == gate 0..3
  const int lane = tid & 63;
  const int q    = lane >> 4;
  const int bl   = lane & 15;

  // XCD-affinity mapping: all 8 slice-blocks of a group share id%8 (one XCD
  // under round-robin dispatch). Perf heuristic only — correctness is scope-safe.
  const int id  = blockIdx.x;
  const int grp = ((id >> 6) << 3) | (id & 7);   // 0..15
  const int s   = (id >> 3) & 7;                 // n-slice 0..7 (32 elems)

  // combiner-role constants: thread (np,b) owns h/c for n = s*32+2np+{0,1}, batch b
  const int np = tid >> 4;                  // 0..15
  const int b  = tid & 15;
  const int nglob   = s * 32 + 2 * np;
  const int bglob_c = grp * 16 + b;

  // ---- W fragments: 2 mtiles x 12 ktiles = 24 frags (spill to AGPR is benign) ----
  short8 wf[24];
  {
    const unsigned short* base =
        wpack + ((size_t)((s * 4 + w) * 24) * 64 + lane) * 8;
#pragma unroll
    for (int f = 0; f < 24; ++f)
      wf[f] = *(const short8*)(base + (size_t)f * 64 * 8);
  }
#pragma unroll
  for (int f = 0; f < 24; ++f)
    asm volatile("" : "+v"(wf[f]));

  // bias for gate w (acc init)
  float4_ bia[2];
#pragma unroll
  for (int m = 0; m < 2; ++m)
    bia[m] = *(const float4_*)(bias + w * 256 + s * 32 + m * 16 + q * 4);

  // c state (combiner role)
  float cst[2];
  cst[0] = c0[(size_t)bglob_c * 256 + nglob];
  cst[1] = c0[(size_t)bglob_c * 256 + nglob + 1];

  // x prefetch for t=0 (ktiles 8..11); B-frag batch = grp*16+bl
  float4_ xr[8];
  {
    const float* xb = x + (size_t)(grp * 16 + bl) * 131072 + q * 8;
#pragma unroll
    for (int kx = 0; kx < 4; ++kx) {
      xr[kx * 2]     = *(const float4_*)(xb + kx * 32);
      xr[kx * 2 + 1] = *(const float4_*)(xb + kx * 32 + 4);
    }
  }

  // hbuf addressing (chunk = ull)
  const size_t hb_base = ((size_t)grp * 16 + bl) * 128;               // consumer
  const size_t my_ch   = ((size_t)grp * 16 + b) * 128 + s * 16 + np;  // producer

  // gate-exchange LDS: [gate][n_local 32][b 16+pad]
  __shared__ float glds[4][32][17];

  float hout[2];

#pragma unroll 1
  for (int t = 0; t < 1024; ++t) {
    // ---- 1. issue poll loads for h_t FIRST (RTT overlaps x-wait + x-MFMAs) ----
    unsigned long long pl[32];
    const unsigned long long* hb = hbuf + (size_t)(t & 3) * SLOT_CH + hb_base;
    const unsigned int tag = (unsigned int)t;
#pragma unroll
    for (int kt = 0; kt < 8; ++kt)
#pragma unroll
      for (int j = 0; j < 4; ++j)
        pl[kt * 4 + j] = __hip_atomic_load(hb + kt * 16 + q * 4 + j,
                                           __ATOMIC_RELAXED,
                                           __HIP_MEMORY_SCOPE_AGENT);

    // ---- 2. convert prefetched x -> bf16 frags (waits only the OLDER x loads) ----
    short8 xf[4];
#pragma unroll
    for (int kx = 0; kx < 4; ++kx) {
      short8 v;
#pragma unroll
      for (int e = 0; e < 4; ++e) {
        v[e]     = (short)f2bf(xr[kx * 2][e]);
        v[e + 4] = (short)f2bf(xr[kx * 2 + 1][e]);
      }
      xf[kx] = v;
    }

    // ---- 3. x-part MFMAs while poll loads are in flight ----
    float4_ acc[2];
#pragma unroll
    for (int m = 0; m < 2; ++m) acc[m] = bia[m];
#pragma unroll
    for (int kx = 0; kx < 4; ++kx)
#pragma unroll
      for (int m = 0; m < 2; ++m)
        acc[m] = __builtin_amdgcn_mfma_f32_16x16x32_bf16(wf[m * 12 + 8 + kx], xf[kx], acc[m], 0, 0, 0);

    // ---- 4. check poll; retry (poll loads are always newest in the vm queue) ----
    for (;;) {
      bool ok = true;
#pragma unroll
      for (int i = 0; i < 32; ++i)
        ok &= ((unsigned int)(pl[i] >> 32) == tag);
      if (__all(ok)) break;
      __builtin_amdgcn_s_sleep(1);
#pragma unroll
      for (int kt = 0; kt < 8; ++kt)
#pragma unroll
        for (int j = 0; j < 4; ++j)
          pl[kt * 4 + j] = __hip_atomic_load(hb + kt * 16 + q * 4 + j,
                                             __ATOMIC_RELAXED,
                                             __HIP_MEMORY_SCOPE_AGENT);
    }
    asm volatile("" ::: "memory");

    // ---- 5. x prefetch for NEXT step (cover = h-MFMAs + combine + store) ----
    {
      int tn = (t < 1023) ? (t + 1) : 1023;
      const float* xb = x + (size_t)(grp * 16 + bl) * 131072 + (size_t)tn * 128 + q * 8;
#pragma unroll
      for (int kx = 0; kx < 4; ++kx) {
        xr[kx * 2]     = *(const float4_*)(xb + kx * 32);
        xr[kx * 2 + 1] = *(const float4_*)(xb + kx * 32 + 4);
      }
    }

    // ---- 6. h-part MFMAs: ktiles 0..7 (B-frag = 4 low dwords of chunks) ----
#pragma unroll
    for (int kt = 0; kt < 8; ++kt) {
      union { unsigned int u[4]; short8 v; } uu;
#pragma unroll
      for (int j = 0; j < 4; ++j)
        uu.u[j] = (unsigned int)pl[kt * 4 + j];
#pragma unroll
      for (int m = 0; m < 2; ++m)
        acc[m] = __builtin_amdgcn_mfma_f32_16x16x32_bf16(wf[m * 12 + kt], uu.v, acc[m], 0, 0, 0);
    }

    // ---- 7. gate exchange + combine ----
#pragma unroll
    for (int m = 0; m < 2; ++m)
#pragma unroll
      for (int r = 0; r < 4; ++r)
        glds[w][m * 16 + q * 4 + r][bl] = acc[m][r];

    __syncthreads();

    unsigned short hp[2];
#pragma unroll
    for (int dn = 0; dn < 2; ++dn) {
      int nl = 2 * np + dn;
      float iv = sigm_(glds[0][nl][b]);
      float fv = sigm_(glds[1][nl][b]);
      float gv = tanh_(glds[2][nl][b]);
      float ov = sigm_(glds[3][nl][b]);
      float cv = fv * cst[dn] + iv * gv;
      cst[dn] = cv;
      float hv = ov * tanh_(cv);
      hout[dn] = hv;
      hp[dn] = f2bf(hv);
    }

    // ---- 8. write h_{t+1}: ONE tagged 8B atomic store, slot (t+1)&3 ----
    {
      unsigned int d = (unsigned int)hp[0] | ((unsigned int)hp[1] << 16);
      unsigned long long hu = (unsigned long long)d
                            | ((unsigned long long)(unsigned int)(t + 1) << 32);
      unsigned long long* dst = hbuf + (size_t)((t + 1) & 3) * SLOT_CH + my_ch;
      __hip_atomic_store(dst, hu, __ATOMIC_RELAXED, __HIP_MEMORY_SCOPE_AGENT);
    }
  }

  // final h (fp32) -> d_out [1,B,H]
  {
    float2_ o2; o2[0] = hout[0]; o2[1] = hout[1];
    *(float2_*)(out + (size_t)bglob_c * 256 + nglob) = o2;
  }
}

extern "C" void kernel_launch(void* const* d_in, const int* in_sizes, int n_in,
                              void* d_out, int out_size, void* d_ws, size_t ws_size,
                              hipStream_t stream) {
  (void)in_sizes; (void)n_in; (void)out_size; (void)ws_size;
  const float* x    = (const float*)d_in[0];
  const float* h0   = (const float*)d_in[1];
  const float* c0   = (const float*)d_in[2];
  const float* w_ih = (const float*)d_in[3];
  const float* w_hh = (const float*)d_in[4];
  const float* b_ih = (const float*)d_in[5];
  const float* b_hh = (const float*)d_in[6];

  char* ws = (char*)d_ws;
  unsigned short*     wpack = (unsigned short*)(ws + WPACK_OFF);
  unsigned long long* hbuf  = (unsigned long long*)(ws + HBUF_OFF);
  float*              bias  = (float*)(ws + BIAS_OFF);

  pack_w<<<192, 256, 0, stream>>>(w_ih, w_hh, wpack);
  init_hb<<<132, 256, 0, stream>>>(h0, b_ih, b_hh, hbuf, bias);
  lstm_main<<<128, 256, 0, stream>>>(x, c0, wpack, bias, hbuf, (float*)d_out);
}

// Round 11
// 5543.713 us; speedup vs baseline: 1.4820x; 1.4737x over previous
//
#include <hip/hip_runtime.h>
#include <hip/hip_bf16.h>

typedef __attribute__((ext_vector_type(8))) short   short8;
typedef __attribute__((ext_vector_type(4))) float   float4_;
typedef __attribute__((ext_vector_type(2))) float   float2_;

// ---------------- workspace layout (bytes) ----------------
#define WPACK_OFF   0
#define WPACK_BYTES 786432                    // 1024 rows x 384 k x 2B, A-frag packed
#define HBUF_OFF    786432
#define HBUF_BYTES  524288                    // 4 slots x 32768 chunks x 4B
#define BIAS_OFF    (HBUF_OFF + HBUF_BYTES)
#define BIAS_BYTES  4096
#define FLAGS_OFF   (BIAS_OFF + BIAS_BYTES)
#define FLAGS_BYTES 1024                      // 16 groups x 8 slice-flags (+pad)

#define SLOT_CH 32768                         // uint chunks per step-slot
// chunk = 2 x bf16 h (4B), ONE relaxed agent store per combiner thread.
// Detection is via per-(grp,slice) FLAGS: producer drains stores at a
// __syncthreads (vmcnt0 before s_barrier), then tid0 sets flag=t+1. Consumer
// polls ONLY the 8 flags (1 load/lane/retry), then one-shot loads the payload
// — loads issue after the flag branch resolves, hence observe post-flag LLC
// state. Skew <=1 step (all-consume-all) -> 4 slots never alias.

__device__ __forceinline__ unsigned short f2bf(float f) {
  unsigned int u = __float_as_uint(f);
  u += 0x7fffu + ((u >> 16) & 1u);            // round-to-nearest-even
  return (unsigned short)(u >> 16);
}

// Pack W = [W_hh | W_ih] into MFMA A-fragment order, bf16.
// idx = ((((s*4+w)*2+m)*12)+kt)*64+lane ; slice s owns rows gate*256 + [s*32,s*32+32).
__global__ void pack_w(const float* __restrict__ w_ih,
                       const float* __restrict__ w_hh,
                       unsigned short* __restrict__ wpack) {
  int idx = blockIdx.x * blockDim.x + threadIdx.x;
  if (idx >= 49152) return;
  int lane = idx & 63;
  int r1 = idx >> 6;
  int kt = r1 % 12;
  int r2 = r1 / 12;
  int m  = r2 & 1;          // mtile within slice (16 rows)
  int r3 = r2 >> 1;
  int w  = r3 & 3;          // gate (i,f,g,o) == wave
  int s  = r3 >> 2;         // slice 0..7
  int row = w * 256 + s * 32 + m * 16 + (lane & 15);
  int q = lane >> 4;
  short8 o;
#pragma unroll
  for (int j = 0; j < 8; ++j) {
    int kk = kt * 32 + q * 8 + j;             // 0..383
    float v = (kt < 8) ? w_hh[row * 256 + kk]
                       : w_ih[row * 128 + (kk - 256)];
    o[j] = (short)f2bf(v);
  }
  *(short8*)(wpack + (size_t)idx * 8) = o;
}

// Seed slot 0 with h0 pairs; bias = b_ih+b_hh. Slots 1..3 are flag-gated, no init.
__global__ void init_hb(const float* __restrict__ h0,
                        const float* __restrict__ b_ih,
                        const float* __restrict__ b_hh,
                        unsigned int* __restrict__ hbuf,
                        float* __restrict__ bias) {
  int idx = blockIdx.x * blockDim.x + threadIdx.x;
  if (idx < 32768) {                           // chunk idx = b_glob*128 + pair
    int b_glob = idx >> 7;
    int p      = idx & 127;
    hbuf[idx] = (unsigned int)f2bf(h0[b_glob * 256 + 2 * p])
              | ((unsigned int)f2bf(h0[b_glob * 256 + 2 * p + 1]) << 16);
  } else if (idx < 33792) {
    int j = idx - 32768;
    bias[j] = b_ih[j] + b_hh[j];
  }
}

__device__ __forceinline__ float sigm_(float v) {
  return 1.f / (1.f + __expf(-v));
}
__device__ __forceinline__ float tanh_(float v) {
  return 1.f - 2.f / (__expf(2.f * v) + 1.f);  // robust at +-inf
}

__global__ __launch_bounds__(256, 1) void lstm_main(
    const float* __restrict__ x, const float* __restrict__ c0,
    const unsigned short* __restrict__ wpack, const float* __restrict__ bias,
    unsigned int* hbuf, int* flags, float* __restrict__ out) {

  const int tid  = threadIdx.x;
  const int w    = tid >> 6;       // wave == gate 0..3
  const int lane = tid & 63;
  const int q    = lane >> 4;
  const int bl   = lane & 15;

  // XCD-affinity: all 8 slice-blocks of a group share id%8 (one XCD under
  // round-robin dispatch). Perf heuristic only — correctness is scope-safe.
  const int id  = blockIdx.x;
  const int grp = ((id >> 6) << 3) | (id & 7);   // 0..15
  const int s   = (id >> 3) & 7;                 // n-slice 0..7 (32 elems)

  // combiner-role constants: thread (np,b) owns h/c for n = s*32+2np+{0,1}, batch b
  const int np = tid >> 4;                  // 0..15
  const int b  = tid & 15;
  const int nglob   = s * 32 + 2 * np;
  const int bglob_c = grp * 16 + b;

  // ---- W fragments: 2 mtiles x 12 ktiles = 24 frags (AGPR spill is benign) ----
  short8 wf[24];
  {
    const unsigned short* base =
        wpack + ((size_t)((s * 4 + w) * 24) * 64 + lane) * 8;
#pragma unroll
    for (int f = 0; f < 24; ++f)
      wf[f] = *(const short8*)(base + (size_t)f * 64 * 8);
  }
#pragma unroll
  for (int f = 0; f < 24; ++f)
    asm volatile("" : "+v"(wf[f]));

  // bias for gate w (acc init)
  float4_ bia[2];
#pragma unroll
  for (int m = 0; m < 2; ++m)
    bia[m] = *(const float4_*)(bias + w * 256 + s * 32 + m * 16 + q * 4);

  // c state (combiner role)
  float cst[2];
  cst[0] = c0[(size_t)bglob_c * 256 + nglob];
  cst[1] = c0[(size_t)bglob_c * 256 + nglob + 1];

  // x prefetch for t=0 (ktiles 8..11); B-frag batch = grp*16+bl
  float4_ xr[8];
  {
    const float* xb = x + (size_t)(grp * 16 + bl) * 131072 + q * 8;
#pragma unroll
    for (int kx = 0; kx < 4; ++kx) {
      xr[kx * 2]     = *(const float4_*)(xb + kx * 32);
      xr[kx * 2 + 1] = *(const float4_*)(xb + kx * 32 + 4);
    }
  }

  // hbuf addressing (uint chunks)
  const size_t hb_base = ((size_t)grp * 16 + bl) * 128;               // consumer
  const size_t my_ch   = ((size_t)grp * 16 + b) * 128 + s * 16 + np;  // producer
  int* const gflags = flags + grp * 8;
  int* const myflag = gflags + s;
  int* const pollp  = gflags + (lane & 7);

  // gate-exchange LDS: [gate][n_local 32][b 16+pad]
  __shared__ float glds[4][32][17];

  float hout[2];

#pragma unroll 1
  for (int t = 0; t < 1024; ++t) {
    // ---- 1. convert prefetched x -> bf16 frags (prev-iter loads: complete) ----
    short8 xf[4];
#pragma unroll
    for (int kx = 0; kx < 4; ++kx) {
      short8 v;
#pragma unroll
      for (int e = 0; e < 4; ++e) {
        v[e]     = (short)f2bf(xr[kx * 2][e]);
        v[e + 4] = (short)f2bf(xr[kx * 2 + 1][e]);
      }
      xf[kx] = v;
    }

    // ---- 2. poll the 8 slice-flags only: ONE 4B load per lane per retry ----
    for (;;) {
      int f = __hip_atomic_load(pollp, __ATOMIC_RELAXED, __HIP_MEMORY_SCOPE_AGENT);
      if (__all(f >= t)) break;
      __builtin_amdgcn_s_sleep(1);
    }
    asm volatile("" ::: "memory");   // chunk loads stay below the flag branch

    // ---- 3. one-shot payload loads (32 x 4B), issued before x work covers RTT ----
    unsigned int pl[32];
    {
      const unsigned int* hb = hbuf + (size_t)(t & 3) * SLOT_CH + hb_base;
#pragma unroll
      for (int kt = 0; kt < 8; ++kt)
#pragma unroll
        for (int j = 0; j < 4; ++j)
          pl[kt * 4 + j] = __hip_atomic_load(hb + kt * 16 + q * 4 + j,
                                             __ATOMIC_RELAXED,
                                             __HIP_MEMORY_SCOPE_AGENT);
    }

    // ---- 4. x prefetch for NEXT step (younger than chunks in vm queue) ----
    {
      int tn = (t < 1023) ? (t + 1) : 1023;
      const float* xb = x + (size_t)(grp * 16 + bl) * 131072 + (size_t)tn * 128 + q * 8;
#pragma unroll
      for (int kx = 0; kx < 4; ++kx) {
        xr[kx * 2]     = *(const float4_*)(xb + kx * 32);
        xr[kx * 2 + 1] = *(const float4_*)(xb + kx * 32 + 4);
      }
    }

    // ---- 5. x-part MFMAs while chunk loads are in flight ----
    float4_ acc[2];
#pragma unroll
    for (int m = 0; m < 2; ++m) acc[m] = bia[m];
#pragma unroll
    for (int kx = 0; kx < 4; ++kx)
#pragma unroll
      for (int m = 0; m < 2; ++m)
        acc[m] = __builtin_amdgcn_mfma_f32_16x16x32_bf16(wf[m * 12 + 8 + kx], xf[kx], acc[m], 0, 0, 0);

    // ---- 6. h-part MFMAs (waits chunks only; x prefetch is younger) ----
#pragma unroll
    for (int kt = 0; kt < 8; ++kt) {
      union { unsigned int u[4]; short8 v; } uu;
#pragma unroll
      for (int j = 0; j < 4; ++j)
        uu.u[j] = pl[kt * 4 + j];
#pragma unroll
      for (int m = 0; m < 2; ++m)
        acc[m] = __builtin_amdgcn_mfma_f32_16x16x32_bf16(wf[m * 12 + kt], uu.v, acc[m], 0, 0, 0);
    }

    // ---- 7. gate exchange + combine ----
#pragma unroll
    for (int m = 0; m < 2; ++m)
#pragma unroll
      for (int r = 0; r < 4; ++r)
        glds[w][m * 16 + q * 4 + r][bl] = acc[m][r];

    __syncthreads();

    unsigned short hp[2];
#pragma unroll
    for (int dn = 0; dn < 2; ++dn) {
      int nl = 2 * np + dn;
      float iv = sigm_(glds[0][nl][b]);
      float fv = sigm_(glds[1][nl][b]);
      float gv = tanh_(glds[2][nl][b]);
      float ov = sigm_(glds[3][nl][b]);
      float cv = fv * cst[dn] + iv * gv;
      cst[dn] = cv;
      float hv = ov * tanh_(cv);
      hout[dn] = hv;
      hp[dn] = f2bf(hv);
    }

    // ---- 8. publish h_{t+1}: 4B chunk store -> barrier (drains vmcnt) -> flag ----
    {
      unsigned int d = (unsigned int)hp[0] | ((unsigned int)hp[1] << 16);
      unsigned int* dst = hbuf + (size_t)((t + 1) & 3) * SLOT_CH + my_ch;
      __hip_atomic_store(dst, d, __ATOMIC_RELAXED, __HIP_MEMORY_SCOPE_AGENT);
    }
    __syncthreads();                 // vmcnt(0) before s_barrier: stores at LLC
    if (tid == 0)
      __hip_atomic_store(myflag, t + 1, __ATOMIC_RELAXED, __HIP_MEMORY_SCOPE_AGENT);
  }

  // final h (fp32) -> d_out [1,B,H]
  {
    float2_ o2; o2[0] = hout[0]; o2[1] = hout[1];
    *(float2_*)(out + (size_t)bglob_c * 256 + nglob) = o2;
  }
}

extern "C" void kernel_launch(void* const* d_in, const int* in_sizes, int n_in,
                              void* d_out, int out_size, void* d_ws, size_t ws_size,
                              hipStream_t stream) {
  (void)in_sizes; (void)n_in; (void)out_size; (void)ws_size;
  const float* x    = (const float*)d_in[0];
  const float* h0   = (const float*)d_in[1];
  const float* c0   = (const float*)d_in[2];
  const float* w_ih = (const float*)d_in[3];
  const float* w_hh = (const float*)d_in[4];
  const float* b_ih = (const float*)d_in[5];
  const float* b_hh = (const float*)d_in[6];

  char* ws = (char*)d_ws;
  unsigned short* wpack = (unsigned short*)(ws + WPACK_OFF);
  unsigned int*   hbuf  = (unsigned int*)(ws + HBUF_OFF);
  float*          bias  = (float*)(ws + BIAS_OFF);
  int*            flags = (int*)(ws + FLAGS_OFF);

  hipMemsetAsync(flags, 0, FLAGS_BYTES, stream);   // flag=0 == h_0 published
  pack_w<<<192, 256, 0, stream>>>(w_ih, w_hh, wpack);
  init_hb<<<132, 256, 0, stream>>>(h0, b_ih, b_hh, hbuf, bias);
  lstm_main<<<128, 256, 0, stream>>>(x, c0, wpack, bias, hbuf, flags,
                                     (float*)d_out);
}